// Round 11
// baseline (217.420 us; speedup 1.0000x reference)
//
#include <hip/hip_runtime.h>
#include <hip/hip_bf16.h>

#define B_ 32
#define T_ 4096
#define H_ 512
#define A_ 512
#define C_ 32
#define KTOT 544            // H + C (conv folded in as K-extension)
#define NKS  (KTOT / 32)    // 17 MFMA k-steps
#define BM   128            // t-rows per block
#define BN   128            // a-cols per block

typedef float f32x4 __attribute__((ext_vector_type(4)));
typedef __bf16 bf16x8 __attribute__((ext_vector_type(8)));

__device__ inline float fast_tanh(float x) {
    // tanh(x) = 1 - 2/(exp(2x)+1); exact at saturation, |err| ~1e-7
    float t = __expf(2.0f * x);
    return 1.0f - 2.0f / (t + 1.0f);
}

__device__ __forceinline__ void async16(const void* g, void* l) {
    __builtin_amdgcn_global_load_lds(
        (const __attribute__((address_space(1))) unsigned int*)g,
        (__attribute__((address_space(3))) unsigned int*)l, 16, 0, 0);
}

// ---------------- prep: dpb = dec@W^T + b ; V,U -> unified bf16 fragment buffer ----
// Vsall[(k>>3)*A + a]*8 + (k&7), k in [0,544). Per-kstep 32KB chunk contiguous.
__global__ __launch_bounds__(256) void prep_kernel(
    const float* __restrict__ dec, const float* __restrict__ W,
    const float* __restrict__ bvec, const float* __restrict__ V,
    const float* __restrict__ U,
    float* __restrict__ dpb, __bf16* __restrict__ Vsall) {
    int id = blockIdx.x * 256 + threadIdx.x;
    const int N1 = B_ * A_;          // 16384
    const int N2 = A_ * H_;          // 262144
    if (id < N1) {
        int b = id / A_, a = id % A_;
        const float* dr = dec + b * H_;
        const float* wr = W + (size_t)a * H_;
        float s = 0.f;
        #pragma unroll 8
        for (int h = 0; h < H_; ++h) s += dr[h] * wr[h];
        dpb[id] = s + bvec[a];
    } else if (id < N1 + N2) {
        int e = id - N1;
        int a = e >> 9, k = e & 511;
        Vsall[((k >> 3) * A_ + a) * 8 + (k & 7)] = (__bf16)V[(size_t)a * H_ + k];
    } else {
        int e = id - N1 - N2;        // 16384 U elements
        int a = e >> 5, c = e & 31;
        int k = H_ + c;
        Vsall[((k >> 3) * A_ + a) * 8 + (k & 7)] = (__bf16)U[a * C_ + c];
    }
}

// ---------------- fused scores: m97-geometry 128x128 blocks, 4 waves of 64x64 ----
// grid 4096; XCD-bijective swizzle; decode: a_tile fastest, then t_tile, then batch.
// Per kstep: A reg-staged (2x f32x8 -> bf16x8 ds_write), B global_load_lds (2/thread).
// Writes PARTIAL scores (per a-tile) to pscore[a_tile][B,T]; softmax sums them.
__global__ __launch_bounds__(256) void scores_mfma(
    const float* __restrict__ enc, const float* __restrict__ align,
    const float* __restrict__ conv_w, const float* __restrict__ conv_b,
    const __bf16* __restrict__ Vsall, const float* __restrict__ dpb,
    const float* __restrict__ wvec, float* __restrict__ pscore) {
    const int bid = blockIdx.x;
    const int swz = (bid & 7) * 512 + (bid >> 3);   // bijective, 4096 % 8 == 0
    const int a_tile = swz & 3;
    const int tb = swz >> 2;
    const int t_tile = tb & 31;
    const int b = tb >> 5;
    const int t0 = t_tile * BM;
    const int acol0 = a_tile * BN;

    const int tid = threadIdx.x;
    const int lane = tid & 63, wid = tid >> 6;
    const int row0 = lane & 15;   // frag row (A) / col (B,C)
    const int kg   = lane >> 4;   // k-group 0..3
    const int wq   = wid & 1;     // col half (64)
    const int wr   = wid >> 1;    // row half (64)

    __shared__ char smem[33792];  // A dbuf 2x8K @0; B dbuf 2x8K @16384; spart 1K @32768
    float* spart = (float*)(smem + 32768);   // [2][128]

    const float* encb = enc + ((size_t)b * T_ + t0) * H_;

    // A staging: thread handles units u0=tid (row grow0) and u1=tid+256 (row grow0+64)
    const int grow0 = tid >> 2;   // 0..63
    const int kq    = tid & 3;
    const int aswz  = ((grow0 >> 1) & 3);
    const int awb0  = grow0 * 64 + ((kq ^ aswz) << 4);   // row swizzle identical for row+64
    // A read byte offsets for the 4 m-frags
    int arbyte[4];
    #pragma unroll
    for (int m = 0; m < 4; ++m) {
        int row = wr * 64 + m * 16 + row0;
        arbyte[m] = row * 64 + ((kg ^ ((row >> 1) & 3)) << 4);
    }
    // B read byte offsets base: unit = kg*128 + wq*64 + n*16 + row0
    const int brbase = (kg * 128 + wq * 64 + row0) * 16;

    // ---- prologue: stage kstep 0 ----
    {
        char* bdst = smem + 16384;
        #pragma unroll
        for (int i = 0; i < 2; ++i) {
            int u = i * 256 + tid;
            int kgB = u >> 7, ac = u & 127;
            async16(Vsall + (size_t)(kgB * 512 + acol0 + ac) * 8, bdst + u * 16);
        }
        const float* p0 = encb + (size_t)grow0 * H_ + kq * 8;
        const float* p1 = p0 + (size_t)64 * H_;
        f32x4 l0 = *reinterpret_cast<const f32x4*>(p0);
        f32x4 h0 = *reinterpret_cast<const f32x4*>(p0 + 4);
        f32x4 l1 = *reinterpret_cast<const f32x4*>(p1);
        f32x4 h1 = *reinterpret_cast<const f32x4*>(p1 + 4);
        bf16x8 v0, v1;
        v0[0]=(__bf16)l0.x; v0[1]=(__bf16)l0.y; v0[2]=(__bf16)l0.z; v0[3]=(__bf16)l0.w;
        v0[4]=(__bf16)h0.x; v0[5]=(__bf16)h0.y; v0[6]=(__bf16)h0.z; v0[7]=(__bf16)h0.w;
        v1[0]=(__bf16)l1.x; v1[1]=(__bf16)l1.y; v1[2]=(__bf16)l1.z; v1[3]=(__bf16)l1.w;
        v1[4]=(__bf16)h1.x; v1[5]=(__bf16)h1.y; v1[6]=(__bf16)h1.z; v1[7]=(__bf16)h1.w;
        *reinterpret_cast<bf16x8*>(smem + awb0) = v0;
        *reinterpret_cast<bf16x8*>(smem + awb0 + 4096) = v1;
    }
    __syncthreads();

    f32x4 acc[4][4];
    #pragma unroll
    for (int m = 0; m < 4; ++m)
        #pragma unroll
        for (int n = 0; n < 4; ++n) acc[m][n] = (f32x4){0.f, 0.f, 0.f, 0.f};

    #pragma unroll
    for (int ks = 0; ks < NKS; ++ks) {
        const int cur = ks & 1;
        char* Acur = smem + cur * 8192;
        char* Anxt = smem + (cur ^ 1) * 8192;
        char* Bcur = smem + 16384 + cur * 8192;
        char* Bnxt = smem + 16384 + (cur ^ 1) * 8192;

        // ---- issue next-kstep stages ----
        f32x4 l0, h0, l1, h1;
        float c00=0.f,c01=0.f,c02=0.f, c10=0.f,c11=0.f,c12=0.f;
        if (ks + 1 < NKS) {
            const __bf16* vchunk = Vsall + (size_t)(ks + 1) * 16384;
            #pragma unroll
            for (int i = 0; i < 2; ++i) {
                int u = i * 256 + tid;
                int kgB = u >> 7, ac = u & 127;
                async16(vchunk + (size_t)(kgB * 512 + acol0 + ac) * 8, Bnxt + u * 16);
            }
            if (ks + 1 < NKS - 1) {
                const float* p0 = encb + (size_t)grow0 * H_ + (ks + 1) * 32 + kq * 8;
                const float* p1 = p0 + (size_t)64 * H_;
                l0 = *reinterpret_cast<const f32x4*>(p0);
                h0 = *reinterpret_cast<const f32x4*>(p0 + 4);
                l1 = *reinterpret_cast<const f32x4*>(p1);
                h1 = *reinterpret_cast<const f32x4*>(p1 + 4);
            } else {
                // conv inputs for A(16): rows grow0 and grow0+64 (clamped reads)
                int t = t0 + grow0;
                int tm = (t > 0) ? t - 1 : 0;
                int tp = t + 1;   // grow0<=63 -> t <= t0+63 < T_-1 safe
                c00 = align[(size_t)b * T_ + tm];
                c01 = align[(size_t)b * T_ + t];
                c02 = align[(size_t)b * T_ + tp];
                if (t == 0) c00 = 0.f;
                int t2 = t + 64;
                int tp2 = (t2 + 1 < T_) ? t2 + 1 : T_ - 1;
                c10 = align[(size_t)b * T_ + t2 - 1];
                c11 = align[(size_t)b * T_ + t2];
                c12 = align[(size_t)b * T_ + tp2];
                if (t2 + 1 == T_) c12 = 0.f;
            }
        }

        // ---- compute kstep ks ----
        bf16x8 afrag[4];
        #pragma unroll
        for (int m = 0; m < 4; ++m)
            afrag[m] = *reinterpret_cast<const bf16x8*>(Acur + arbyte[m]);
        #pragma unroll
        for (int n = 0; n < 4; ++n) {
            bf16x8 bfrag = *reinterpret_cast<const bf16x8*>(Bcur + brbase + n * 256);
            #pragma unroll
            for (int m = 0; m < 4; ++m)
                acc[m][n] = __builtin_amdgcn_mfma_f32_16x16x32_bf16(afrag[m], bfrag, acc[m][n], 0, 0, 0);
        }

        // ---- write A(ks+1) ----
        if (ks + 1 < NKS) {
            bf16x8 v0, v1;
            if (ks + 1 < NKS - 1) {
                v0[0]=(__bf16)l0.x; v0[1]=(__bf16)l0.y; v0[2]=(__bf16)l0.z; v0[3]=(__bf16)l0.w;
                v0[4]=(__bf16)h0.x; v0[5]=(__bf16)h0.y; v0[6]=(__bf16)h0.z; v0[7]=(__bf16)h0.w;
                v1[0]=(__bf16)l1.x; v1[1]=(__bf16)l1.y; v1[2]=(__bf16)l1.z; v1[3]=(__bf16)l1.w;
                v1[4]=(__bf16)h1.x; v1[5]=(__bf16)h1.y; v1[6]=(__bf16)h1.z; v1[7]=(__bf16)h1.w;
            } else {
                #pragma unroll
                for (int e = 0; e < 8; ++e) {
                    int c = kq * 8 + e;
                    float w0 = conv_w[c * 3], w1 = conv_w[c * 3 + 1], w2 = conv_w[c * 3 + 2];
                    float cb = conv_b[c];
                    v0[e] = (__bf16)(cb + w0 * c00 + w1 * c01 + w2 * c02);
                    v1[e] = (__bf16)(cb + w0 * c10 + w1 * c11 + w2 * c12);
                }
            }
            *reinterpret_cast<bf16x8*>(Anxt + awb0) = v0;
            *reinterpret_cast<bf16x8*>(Anxt + awb0 + 4096) = v1;
        }
        __syncthreads();
    }

    // ---- epilogue: tanh(acc + dpb)*w, reduce over this block's 128 a-cols ----
    float dval[4], wv[4];
    #pragma unroll
    for (int n = 0; n < 4; ++n) {
        int a = acol0 + wq * 64 + n * 16 + row0;
        dval[n] = dpb[b * A_ + a];
        wv[n]   = wvec[a];
    }
    #pragma unroll
    for (int m = 0; m < 4; ++m) {
        float rs[4] = {0.f, 0.f, 0.f, 0.f};
        #pragma unroll
        for (int n = 0; n < 4; ++n) {
            #pragma unroll
            for (int j = 0; j < 4; ++j) {
                float x = acc[m][n][j] + dval[n];
                rs[j] += fast_tanh(x) * wv[n];
            }
        }
        #pragma unroll
        for (int j = 0; j < 4; ++j) {
            float v = rs[j];
            v += __shfl_xor(v, 1);
            v += __shfl_xor(v, 2);
            v += __shfl_xor(v, 4);
            v += __shfl_xor(v, 8);
            if (row0 == 0) spart[wq * BM + wr * 64 + m * 16 + kg * 4 + j] = v;
        }
    }
    __syncthreads();
    if (tid < BM) {
        float s = spart[tid] + spart[BM + tid];
        pscore[(size_t)a_tile * (B_ * T_) + (size_t)b * T_ + t0 + tid] = s;
    }
}

// ---------------- softmax over T per batch; sums the 4 a-tile partials ----------------
__global__ __launch_bounds__(256) void softmax_k(
    const float* __restrict__ pscore, float* __restrict__ out_align) {
    int b = blockIdx.x;
    int tid = threadIdx.x;
    __shared__ float redm[4];
    __shared__ float reds[4];
    float local[16];
    float mx = -1e30f;
    #pragma unroll
    for (int i = 0; i < 16; ++i) {
        int idx = b * T_ + tid + i * 256;
        float s = pscore[idx] + pscore[B_ * T_ + idx]
                + pscore[2 * B_ * T_ + idx] + pscore[3 * B_ * T_ + idx];
        local[i] = s;
        mx = fmaxf(mx, s);
    }
    for (int off = 32; off >= 1; off >>= 1) mx = fmaxf(mx, __shfl_xor(mx, off));
    if ((tid & 63) == 0) redm[tid >> 6] = mx;
    __syncthreads();
    mx = fmaxf(fmaxf(redm[0], redm[1]), fmaxf(redm[2], redm[3]));
    float sum = 0.f;
    #pragma unroll
    for (int i = 0; i < 16; ++i) { local[i] = __expf(local[i] - mx); sum += local[i]; }
    for (int off = 32; off >= 1; off >>= 1) sum += __shfl_xor(sum, off);
    if ((tid & 63) == 0) reds[tid >> 6] = sum;
    __syncthreads();
    sum = reds[0] + reds[1] + reds[2] + reds[3];
    float inv = 1.0f / sum;
    #pragma unroll
    for (int i = 0; i < 16; ++i)
        out_align[b * T_ + tid + i * 256] = local[i] * inv;
}

// ---------------- pout[b,chunk,h] = sum_{t in chunk} alpha * enc ----------------
__global__ __launch_bounds__(512) void pout_k(
    const float* __restrict__ enc, const float* __restrict__ alpha,
    float* __restrict__ pout) {
    int chunk = blockIdx.x;   // 0..7 (512 rows each)
    int b = blockIdx.y;
    int tid = threadIdx.x;
    int t0 = chunk * 512;
    __shared__ float as[512];
    as[tid] = alpha[b * T_ + t0 + tid];
    __syncthreads();
    float acc = 0.f;
    const float* ep = enc + ((size_t)b * T_ + t0) * H_ + tid;
    #pragma unroll 4
    for (int t = 0; t < 512; ++t) acc += as[t] * ep[(size_t)t * H_];
    pout[((size_t)b * 8 + chunk) * H_ + tid] = acc;
}

__global__ __launch_bounds__(512) void combine_k(
    const float* __restrict__ pout, float* __restrict__ out) {
    int b = blockIdx.x; int h = threadIdx.x;
    float s = 0.f;
    #pragma unroll
    for (int c = 0; c < 8; ++c) s += pout[((size_t)b * 8 + c) * H_ + h];
    out[b * H_ + h] = s;
}

extern "C" void kernel_launch(void* const* d_in, const int* in_sizes, int n_in,
                              void* d_out, int out_size, void* d_ws, size_t ws_size,
                              hipStream_t stream) {
    const float* dec    = (const float*)d_in[0];
    const float* enc    = (const float*)d_in[1];
    const float* align  = (const float*)d_in[2];
    const float* conv_w = (const float*)d_in[3];
    const float* conv_b = (const float*)d_in[4];
    const float* W      = (const float*)d_in[5];
    const float* V      = (const float*)d_in[6];
    const float* U      = (const float*)d_in[7];
    const float* bvec   = (const float*)d_in[8];
    const float* wvec   = (const float*)d_in[9];
    float* out       = (float*)d_out;           // output[B,H] fp32
    float* out_align = out + B_ * H_;           // alignment[B,T] fp32

    char* ws = (char*)d_ws;
    float*  dpb    = (float*)(ws);                    // 64 KB
    float*  pscore = (float*)(ws + (64 << 10));       // 4 x 512 KB = 2 MB
    float*  pout   = (float*)(ws + (64 << 10) + (2 << 20));          // 512 KB
    __bf16* Vsall  = (__bf16*)(ws + (64 << 10) + (2 << 20) + (512 << 10));  // 544 KB

    prep_kernel<<<(B_ * A_ + A_ * H_ + A_ * C_) / 256, 256, 0, stream>>>(
        dec, W, bvec, V, U, dpb, Vsall);
    scores_mfma<<<(T_ / BM) * (A_ / BN) * B_, 256, 0, stream>>>(
        enc, align, conv_w, conv_b, Vsall, dpb, wvec, pscore);
    softmax_k<<<B_, 256, 0, stream>>>(pscore, out_align);
    pout_k<<<dim3(8, B_), 512, 0, stream>>>(enc, out_align, pout);
    combine_k<<<B_, 512, 0, stream>>>(pout, out);
}